// Round 18
// baseline (220.459 us; speedup 1.0000x reference)
//
#include <hip/hip_runtime.h>
#include <math.h>

#define EMBED 768
#define NHEADS 12
#define HDIM 64
#define SEQ 1025
#define NBATCH 8
#define BHCOUNT (NBATCH*NHEADS)   // 96
#define MROWS (NBATCH*SEQ)        // 8200
#define QKV_N (3*EMBED)           // 2304
#define QKV_ELEMS (BHCOUNT*SEQ*HDIM)  // 6,297,600 elems (== MROWS*EMBED)
#define BT_N 3969                 // (2*32-1)^2
#define MASKPAD 1088              // 4-aligned padded mask row
// q pre-scale = 0.125 * log2(e): softmax runs in exp2 domain
#define QMUL 0.1803368801111204f
#define LOG2E 1.4426950408889634f
#define NX4 1574400               // MROWS*EMBED/4
#define NW4 442368                // QKV_N*EMBED/4
#define NP4 147456                // EMBED*EMBED/4

typedef __attribute__((ext_vector_type(8))) short bf16x8;
typedef __attribute__((ext_vector_type(4))) float f32x4;
typedef __attribute__((ext_vector_type(16))) float f32x16;
typedef __attribute__((ext_vector_type(4))) unsigned int u32x4;

#define FM3(a,b,c) fmaxf(fmaxf((a),(b)),(c))

static __device__ inline unsigned short f2bf(float f) {
    unsigned u = __float_as_uint(f);
    unsigned r = (u + 0x7FFF + ((u >> 16) & 1)) >> 16;   // RNE
    return (unsigned short)r;
}

// HW pack: two f32 -> one u32 of 2x bf16 (RNE), single VALU op (T12 recipe)
static __device__ inline unsigned int cvtpk(float a, float b) {
    unsigned int r;
    asm("v_cvt_pk_bf16_f32 %0, %1, %2" : "=v"(r) : "v"(a), "v"(b));
    return r;
}

// async global->LDS, 16B per lane, linear LDS dest (wave-uniform base + lane*16)
static __device__ inline void gld16(const unsigned short* g, unsigned short* l) {
    __builtin_amdgcn_global_load_lds(
        (const __attribute__((address_space(1))) unsigned int*)g,
        (__attribute__((address_space(3))) unsigned int*)l,
        16, 0, 0);
}

// ---------------- merged fp32 -> bf16 convert for x, qkv_w, proj_w ----------------
__global__ __launch_bounds__(256)
void f2bf3_kernel(const float* __restrict__ x, const float* __restrict__ w,
                  const float* __restrict__ pw,
                  unsigned short* __restrict__ xbf, unsigned short* __restrict__ wbf,
                  unsigned short* __restrict__ pwbf)
{
    int i = blockIdx.x * 256 + threadIdx.x;   // float4-group index
    const float* src; unsigned short* dst; int off;
    if (i < NX4)            { src = x;  dst = xbf;  off = i; }
    else if (i < NX4 + NW4) { src = w;  dst = wbf;  off = i - NX4; }
    else if (i < NX4 + NW4 + NP4) { src = pw; dst = pwbf; off = i - NX4 - NW4; }
    else return;
    float4 v = *reinterpret_cast<const float4*>(&src[off << 2]);
    ushort4 o;
    o.x = f2bf(v.x); o.y = f2bf(v.y); o.z = f2bf(v.z); o.w = f2bf(v.w);
    *reinterpret_cast<ushort4*>(&dst[off << 2]) = o;
}

// ---------------- merged tables: rope cos/sin + btT (scaled) + mask pad ----------------
__global__ __launch_bounds__(256)
void setup_tables_kernel(const float* __restrict__ bt, float* __restrict__ btT,
                         const unsigned char* __restrict__ m, unsigned char* __restrict__ mp,
                         float* __restrict__ cosT, float* __restrict__ sinT)
{
    const int bid = blockIdx.x, tid = threadIdx.x;
    if (bid < 256) {                       // rope: 4 s-values per block
        int s = (bid << 2) + (tid >> 6);
        int d = tid & 63;
        int pos = (d < 32) ? (s >> 5) : (s & 31);
        int j = (d & 31) >> 1;
        float ang = (float)pos * expf(-(float)j * 0.5756462732485115f);
        cosT[(s << 6) + d] = cosf(ang);
        sinT[(s << 6) + d] = sinf(ang);
    } else if (bid < 256 + 187) {          // btT: 12*3969 elems
        int e = (bid - 256) * 256 + tid;
        if (e < NHEADS * BT_N) {
            int h = e / BT_N, idx = e - h * BT_N;
            btT[h * BT_N + idx] = bt[idx * NHEADS + h] * LOG2E;
        }
    } else {                               // mask pad: 8 blocks
        int b = bid - 443;
        for (int i = tid; i < MASKPAD; i += 256)
            mp[b * MASKPAD + i] = (i < SEQ) ? m[b * SEQ + i] : (unsigned char)0;
    }
}

// ---------------- QKV GEMM (bf16 MFMA, BK=64, T2-swizzled LDS) ----------------
// 128x128 tile, 12 K-iters of 64; As/Bs rows 128B -> XOR-swizzle slot^((row^(row>>3))&7),
// written via pre-swizzled gld16 SOURCE (LDS dest linear), read with the same involution.
__global__ __launch_bounds__(256)
void qkv_mfma_kernel(const unsigned short* __restrict__ xbf,
                     const unsigned short* __restrict__ wbf,
                     const float* __restrict__ bias,
                     const float* __restrict__ cosT, const float* __restrict__ sinT,
                     unsigned short* __restrict__ qout, unsigned short* __restrict__ kout,
                     unsigned short* __restrict__ vout)
{
    __shared__ unsigned short As[128][64];
    __shared__ unsigned short Bs[128][64];
    const int m0 = blockIdx.x * 128;
    const int n0 = blockIdx.y * 128;
    const int tid = threadIdx.x;
    const int w = tid >> 6, lane = tid & 63;
    const int li = lane & 15, lg = lane >> 4;
    const int wr = w >> 1, wc = w & 1;

    f32x4 acc[4][4];
    #pragma unroll
    for (int mi = 0; mi < 4; ++mi)
        #pragma unroll
        for (int nj = 0; nj < 4; ++nj) acc[mi][nj] = (f32x4){0.f, 0.f, 0.f, 0.f};

    for (int kt = 0; kt < 12; ++kt) {
        const int k0 = kt << 6;
        #pragma unroll
        for (int c = 0; c < 4; ++c) {
            const int idx = c * 256 + tid;        // 0..1023
            const int row = idx >> 3, slot = idx & 7;
            const int ss = (slot ^ ((row ^ (row >> 3)) & 7)) << 3;   // swizzled ushort col
            int grow = m0 + row; if (grow > MROWS - 1) grow = MROWS - 1;
            gld16(&xbf[(long)grow * EMBED + k0 + ss], &As[0][0] + idx * 8);
            gld16(&wbf[(long)(n0 + row) * EMBED + k0 + ss], &Bs[0][0] + idx * 8);
        }
        __syncthreads();

        __builtin_amdgcn_s_setprio(1);
        #pragma unroll
        for (int kk = 0; kk < 2; ++kk) {
            bf16x8 af[4], bfr[4];
            #pragma unroll
            for (int mi = 0; mi < 4; ++mi) {
                const int row = wr * 64 + mi * 16 + li;
                const int s = ((kk * 4 + lg) ^ ((row ^ (row >> 3)) & 7)) << 3;
                af[mi] = *reinterpret_cast<const bf16x8*>(&As[row][s]);
            }
            #pragma unroll
            for (int nj = 0; nj < 4; ++nj) {
                const int row = wc * 64 + nj * 16 + li;
                const int s = ((kk * 4 + lg) ^ ((row ^ (row >> 3)) & 7)) << 3;
                bfr[nj] = *reinterpret_cast<const bf16x8*>(&Bs[row][s]);
            }
            #pragma unroll
            for (int mi = 0; mi < 4; ++mi)
                #pragma unroll
                for (int nj = 0; nj < 4; ++nj)
                    acc[mi][nj] = __builtin_amdgcn_mfma_f32_16x16x32_bf16(
                        af[mi], bfr[nj], acc[mi][nj], 0, 0, 0);
        }
        __builtin_amdgcn_s_setprio(0);
        __syncthreads();
    }

    int brow[4][4], srow[4][4];
    #pragma unroll
    for (int mi = 0; mi < 4; ++mi)
        #pragma unroll
        for (int r = 0; r < 4; ++r) {
            int m = m0 + wr * 64 + mi * 16 + lg * 4 + r;
            int mm = (m < MROWS) ? m : (MROWS - 1);
            int bb = mm / SEQ;
            brow[mi][r] = bb;
            srow[mi][r] = mm - bb * SEQ;
        }

    #pragma unroll
    for (int nj = 0; nj < 4; ++nj) {
        const int n = n0 + wc * 64 + nj * 16 + li;
        const int which = n / EMBED;
        const int nh = n - which * EMBED;
        const int h = nh >> 6, d = nh & 63;
        unsigned short* outp = (which == 0) ? qout : (which == 1) ? kout : vout;
        const float mul = (which == 0) ? QMUL : 1.0f;
        const float bn = bias[n];
        const bool dorope = which < 2;
        const float sgn = (d & 1) ? 1.f : -1.f;
        #pragma unroll
        for (int mi = 0; mi < 4; ++mi)
            #pragma unroll
            for (int r = 0; r < 4; ++r) {
                const int m = m0 + wr * 64 + mi * 16 + lg * 4 + r;
                float v = acc[mi][nj][r] + bn;
                float pv = __shfl_xor(v, 1, 64);
                if (m < MROWS) {
                    const int bb = brow[mi][r], s = srow[mi][r];
                    if (dorope && s >= 1) {
                        const int p = s - 1;
                        v = v * cosT[(p << 6) + d] + sgn * pv * sinT[(p << 6) + d];
                    }
                    outp[((long)(bb * NHEADS + h) * SEQ + s) * HDIM + d] = f2bf(v * mul);
                }
            }
    }
}

// ---------------- Flash attention: 32x32 MFMA, in-register P, bias-in-C, scalar mask ----------------
// grid 864 = 9 q-tiles x 96 bh, XCD-clustered: xcd=i&7, jb=i>>3, bh=xcd*12+jb%12,
// q0=(jb/12)*128. Block 256 (4 waves); wave w owns q rows q0+w*32..+31.
// S^T C-layout: accs[j][reg] = S[q = w*32 + (lane&31)][kv = j*32 + (reg&3)+8*(reg>>2)+4*(lane>>5)].
__global__ __launch_bounds__(256)
void attn_mfma_kernel(const unsigned short* __restrict__ qg,
                      const unsigned short* __restrict__ kg,
                      const unsigned short* __restrict__ vg,
                      const float* __restrict__ btT,
                      const unsigned char* __restrict__ maskpad,
                      unsigned short* __restrict__ ctx)
{
    __shared__ unsigned short Ks[2][64][64];    // [buf][kv][d], col ^= ((row^(row>>3))&7)<<3
    __shared__ unsigned short Vts[2][64][64];   // [buf][d][kv], col ^= ((row^(row>>3))&7)<<3

    const int i = (int)blockIdx.x;
    const int xcd = i & 7, jb = i >> 3;
    const int bh = xcd * 12 + (jb % 12);
    const int q0 = (jb / 12) * 128;
    const int b = bh / NHEADS, h = bh % NHEADS;
    const int tid = threadIdx.x;
    const int w = tid >> 6;
    const int lane = tid & 63;
    const int l31 = lane & 31;
    const int hi = lane >> 5;

    const unsigned short* qbase = qg + (long)bh * (SEQ * HDIM);
    const unsigned short* kbase = kg + (long)bh * (SEQ * HDIM);
    const unsigned short* vbase = vg + (long)bh * (SEQ * HDIM);
    const unsigned char* maskp = maskpad + b * MASKPAD;
    const float* btTh = btT + h * BT_N;

    // staging geometry (per thread): 2 chunks, row = idx>>3, col8 = (idx&7)*8
    const int sidx0 = tid, sidx1 = 256 + tid;
    const int sr0 = sidx0 >> 3, sc0 = (sidx0 & 7) << 3;
    const int sr1 = sidx1 >> 3, sc1 = (sidx1 & 7) << 3;
    const int kswz0 = ((sr0 ^ (sr0 >> 3)) & 7) << 3;
    const int kswz1 = ((sr1 ^ (sr1 >> 3)) & 7) << 3;

    // ---- prologue: tile-0 K via gld16 (pre-swizzled src), tile-0 V to regs, Q to regs ----
    gld16(&kbase[(long)sr0 * HDIM + (sc0 ^ kswz0)], &Ks[0][0][0] + sidx0 * 8);
    gld16(&kbase[(long)sr1 * HDIM + (sc1 ^ kswz1)], &Ks[0][0][0] + sidx1 * 8);
    int4 vreg[2];
    vreg[0] = *reinterpret_cast<const int4*>(&vbase[(long)sr0 * HDIM + sc0]);
    vreg[1] = *reinterpret_cast<const int4*>(&vbase[(long)sr1 * HDIM + sc1]);

    const int qrow = (w << 5) + l31;
    const int qi_l = q0 + qrow;
    const int qiq = (qi_l > SEQ - 1) ? (SEQ - 1) : qi_l;
    bf16x8 qf[4];   // B-operand: col q = l31, k-run d = s*16 + hi*8 + 0..7
    #pragma unroll
    for (int s = 0; s < 4; ++s)
        qf[s] = *reinterpret_cast<const bf16x8*>(&qbase[(long)qiq * HDIM + s * 16 + hi * 8]);

    const float bq = (qi_l >= 1) ? 1.0f : 0.0f;
    int qp = qi_l - 1; if (qp < 0) qp = 0; if (qp > 1023) qp = 1023;
    const int qcode = (qp >> 5) * 63 + (qp & 31) + 1984;

    __syncthreads();   // K0 gld16 landed (barrier drains vmcnt); vreg ready
    {
        union { int4 v; unsigned short u[8]; } t0, t1;
        t0.v = vreg[0]; t1.v = vreg[1];
        const int cb30 = sc0 >> 3, cb31 = sc1 >> 3;
        #pragma unroll
        for (int e = 0; e < 8; ++e) {
            Vts[0][sc0 + e][sr0 ^ (((e ^ cb30) & 7) << 3)] = t0.u[e];
            Vts[0][sc1 + e][sr1 ^ (((e ^ cb31) & 7) << 3)] = t1.u[e];
        }
    }
    __syncthreads();   // tile 0 fully staged

    float m_l = -1e30f, l_l = 0.f;
    f32x16 acco[2];    // O[q=(reg&3)+8(reg>>2)+4hi][d = j2*32 + l31]
    #pragma unroll
    for (int r = 0; r < 16; ++r) { acco[0][r] = 0.f; acco[1][r] = 0.f; }

    int kcb[2][4];     // incremental bias code base per (j, quad)
    for (int kt = 0; kt < 17; ++kt) {
        const int k0 = kt * 64;
        const int cur = kt & 1;

        // ---- (1) prefetch next tile's K (gld16) + V (regs) ----
        if (kt < 16) {
            const int k0n = k0 + 64;
            vreg[0] = (k0n + sr0 < SEQ)
                ? *reinterpret_cast<const int4*>(&vbase[(long)(k0n + sr0) * HDIM + sc0])
                : make_int4(0, 0, 0, 0);
            vreg[1] = (k0n + sr1 < SEQ)
                ? *reinterpret_cast<const int4*>(&vbase[(long)(k0n + sr1) * HDIM + sc1])
                : make_int4(0, 0, 0, 0);
            int ki0 = k0n + sr0; if (ki0 > SEQ - 1) ki0 = SEQ - 1;
            int ki1 = k0n + sr1; if (ki1 > SEQ - 1) ki1 = SEQ - 1;
            gld16(&kbase[(long)ki0 * HDIM + (sc0 ^ kswz0)], &Ks[cur ^ 1][0][0] + sidx0 * 8);
            gld16(&kbase[(long)ki1 * HDIM + (sc1 ^ kswz1)], &Ks[cur ^ 1][0][0] + sidx1 * 8);
        }

        // ---- (2)+(3) bias values; mask via wave-uniform scalar screen on interior tiles ----
        float bvf[2][16];
        unsigned int b4[2][4];
        unsigned int anym = 0;
        const bool interior = (kt >= 1 && kt <= 15);
        if (interior) {
            // wave-uniform mask check: 4 uniform uint4 loads + SALU OR-reduce
            const uint4 ma_ = *reinterpret_cast<const uint4*>(&maskp[k0]);
            const uint4 mb_ = *reinterpret_cast<const uint4*>(&maskp[k0 + 16]);
            const uint4 mc_ = *reinterpret_cast<const uint4*>(&maskp[k0 + 32]);
            const uint4 md_ = *reinterpret_cast<const uint4*>(&maskp[k0 + 48]);
            anym = (ma_.x | ma_.y | ma_.z | ma_.w) | (mb_.x | mb_.y | mb_.z | mb_.w) |
                   (mc_.x | mc_.y | mc_.z | mc_.w) | (md_.x | md_.y | md_.z | md_.w);
            #pragma unroll
            for (int j = 0; j < 2; ++j)
                #pragma unroll
                for (int t = 0; t < 4; ++t) {
                    kcb[j][t] += 126;
                    const int base = qcode - kcb[j][t];   // r=0 index, in [0,3968]
                    if (t == 0 && hi == 0) {
                        // crossing: codes c, c+32, c+33, c+34
                        float4 f = *reinterpret_cast<const float4*>(&btTh[base - 34]);
                        bvf[j][0] = btTh[base]; bvf[j][1] = f.z;
                        bvf[j][2] = f.y;        bvf[j][3] = f.x;
                    } else {
                        float4 f = *reinterpret_cast<const float4*>(&btTh[base - 3]);
                        bvf[j][t * 4 + 0] = f.w; bvf[j][t * 4 + 1] = f.z;
                        bvf[j][t * 4 + 2] = f.y; bvf[j][t * 4 + 3] = f.x;
                    }
                }
        } else {
            #pragma unroll
            for (int j = 0; j < 2; ++j)
                #pragma unroll
                for (int t = 0; t < 4; ++t) {
                    unsigned int bb = 0;
                    #pragma unroll
                    for (int ri = 0; ri < 4; ++ri) {
                        const int ki = k0 + j * 32 + t * 8 + hi * 4 + ri;
                        const int kic = (ki > SEQ - 1) ? (SEQ - 1) : ki;
                        unsigned int dead = (ki >= SEQ) ? 1u : (unsigned int)maskp[kic];
                        bb |= (dead ? 1u : 0u) << (ri * 8);
                        int kp = ki - 1; if (kp < 0) kp = 0; if (kp > 1023) kp = 1023;
                        const int kcv = (kp >> 5) * 63 + (kp & 31);
                        bvf[j][t * 4 + ri] = btTh[qcode - kcv];
                    }
                    b4[j][t] = bb;
                    if (kt == 0) {
                        // seed exact chain with UNCLAMPED kp (kv=0 -> -32); CLS handled below
                        const int kp0 = j * 32 + t * 8 + hi * 4 - 1;
                        kcb[j][t] = (kp0 >> 5) * 63 + (kp0 & 31);
                    }
                }
        }

        // ---- (4) S^T = K · Q^T (32x32x16), bias pre-loaded into the C-operand ----
        if (kt == 0 && hi == 0) bvf[0][0] = 0.0f;   // CLS column kv=0: no bias for any q
        f32x16 accs[2];
        #pragma unroll
        for (int j = 0; j < 2; ++j)
            #pragma unroll
            for (int r = 0; r < 16; ++r)
                accs[j][r] = bvf[j][r] * bq;
        __builtin_amdgcn_s_setprio(1);
        #pragma unroll
        for (int j = 0; j < 2; ++j) {
            const int rswz = ((l31 ^ (j * 4 + (l31 >> 3))) & 7) << 3;
            const unsigned short* krow = &Ks[cur][j * 32 + l31][0];
            #pragma unroll
            for (int s = 0; s < 4; ++s) {
                bf16x8 kf = *reinterpret_cast<const bf16x8*>(&krow[(s * 16 + hi * 8) ^ rswz]);
                accs[j] = __builtin_amdgcn_mfma_f32_32x32x16_bf16(kf, qf[s], accs[j], 0, 0, 0);
            }
        }
        __builtin_amdgcn_s_setprio(0);

        // ---- (5) mask application (cold paths only) ----
        if (interior) {
            if (anym) {   // wave-uniform, rare
                #pragma unroll
                for (int j = 0; j < 2; ++j)
                    #pragma unroll
                    for (int t = 0; t < 4; ++t)
                        #pragma unroll
                        for (int ri = 0; ri < 4; ++ri)
                            if (maskp[k0 + j * 32 + t * 8 + hi * 4 + ri])
                                accs[j][t * 4 + ri] = -1e30f;
            }
        } else {
            if (__any((b4[0][0] | b4[0][1] | b4[0][2] | b4[0][3] |
                       b4[1][0] | b4[1][1] | b4[1][2] | b4[1][3]) != 0)) {
                #pragma unroll
                for (int j = 0; j < 2; ++j)
                    #pragma unroll
                    for (int r = 0; r < 16; ++r)
                        if ((b4[j][r >> 2] >> ((r & 3) * 8)) & 0xFF) accs[j][r] = -1e30f;
            }
        }

        // ---- (6) in-register row softmax (v_max3 tree) with defer-max ----
        float t0 = FM3(accs[0][0],  accs[0][1],  accs[0][2]);
        float t1 = FM3(accs[0][3],  accs[0][4],  accs[0][5]);
        float t2 = FM3(accs[0][6],  accs[0][7],  accs[0][8]);
        float t3 = FM3(accs[0][9],  accs[0][10], accs[0][11]);
        float t4 = FM3(accs[0][12], accs[0][13], accs[0][14]);
        float t5 = FM3(accs[0][15], accs[1][0],  accs[1][1]);
        float t6 = FM3(accs[1][2],  accs[1][3],  accs[1][4]);
        float t7 = FM3(accs[1][5],  accs[1][6],  accs[1][7]);
        float t8 = FM3(accs[1][8],  accs[1][9],  accs[1][10]);
        float t9 = FM3(accs[1][11], accs[1][12], accs[1][13]);
        float u0 = FM3(t0, t1, t2);
        float u1 = FM3(t3, t4, t5);
        float u2 = FM3(t6, t7, t8);
        float u3 = FM3(t9, accs[1][14], accs[1][15]);
        float mx = fmaxf(FM3(u0, u1, u2), u3);
        mx = fmaxf(mx, __shfl_xor(mx, 32, 64));
        if (__any(mx > m_l + 8.0f)) {
            const float mnew = fmaxf(m_l, mx);
            const float alpha = __builtin_amdgcn_exp2f(m_l - mnew);
            #pragma unroll
            for (int r = 0; r < 16; ++r) {
                const float al = __shfl(alpha, (r & 3) + 8 * (r >> 2) + 4 * hi, 64);
                acco[0][r] *= al;
                acco[1][r] *= al;
            }
            l_l *= alpha;
            m_l = mnew;
        }
        float rs = 0.f;
        #pragma unroll
        for (int j = 0; j < 2; ++j)
            #pragma unroll
            for (int r = 0; r < 16; ++r) {
                accs[j][r] = __builtin_amdgcn_exp2f(accs[j][r] - m_l);
                rs += accs[j][r];
            }
        rs += __shfl_xor(rs, 32, 64);
        l_l += rs;

        // ---- (6b) P -> bf16 A-fragments in-register: 16 cvt_pk + 8 permlane32_swap ----
        unsigned int W[2][8];
        #pragma unroll
        for (int j = 0; j < 2; ++j)
            #pragma unroll
            for (int p = 0; p < 8; ++p)
                W[j][p] = cvtpk(accs[j][2 * p], accs[j][2 * p + 1]);
        #pragma unroll
        for (int j = 0; j < 2; ++j)
            #pragma unroll
            for (int sg = 0; sg < 2; ++sg) {
                unsigned int a0 = W[j][4 * sg + 0], a2 = W[j][4 * sg + 2];
                asm volatile("v_permlane32_swap_b32 %0, %1" : "+v"(a0), "+v"(a2));
                W[j][4 * sg + 0] = a0; W[j][4 * sg + 2] = a2;
                unsigned int a1 = W[j][4 * sg + 1], a3 = W[j][4 * sg + 3];
                asm volatile("v_permlane32_swap_b32 %0, %1" : "+v"(a1), "+v"(a3));
                W[j][4 * sg + 1] = a1; W[j][4 * sg + 3] = a3;
            }

        // ---- (7) PV: O += P · V (32x32x16) ----
        __builtin_amdgcn_s_setprio(1);
        #pragma unroll
        for (int j2 = 0; j2 < 2; ++j2) {
            const int vswz = ((l31 ^ (j2 * 4 + (l31 >> 3))) & 7) << 3;
            const unsigned short* vrow = &Vts[cur][j2 * 32 + l31][0];
            #pragma unroll
            for (int s = 0; s < 4; ++s) {
                bf16x8 vf = *reinterpret_cast<const bf16x8*>(&vrow[(s * 16 + hi * 8) ^ vswz]);
                u32x4 aw;
                aw[0] = W[s >> 1][4 * (s & 1) + 0];
                aw[1] = W[s >> 1][4 * (s & 1) + 1];
                aw[2] = W[s >> 1][4 * (s & 1) + 2];
                aw[3] = W[s >> 1][4 * (s & 1) + 3];
                bf16x8 pa = __builtin_bit_cast(bf16x8, aw);
                acco[j2] = __builtin_amdgcn_mfma_f32_32x32x16_bf16(pa, vf, acco[j2], 0, 0, 0);
            }
        }
        __builtin_amdgcn_s_setprio(0);

        // ---- (8) drain V regs into next buffer; single barrier per tile ----
        if (kt < 16) {
            union { int4 v; unsigned short u[8]; } t0v, t1v;
            t0v.v = vreg[0]; t1v.v = vreg[1];
            const int cb30 = sc0 >> 3, cb31 = sc1 >> 3;
            #pragma unroll
            for (int e = 0; e < 8; ++e) {
                Vts[cur ^ 1][sc0 + e][sr0 ^ (((e ^ cb30) & 7) << 3)] = t0v.u[e];
                Vts[cur ^ 1][sc1 + e][sr1 ^ (((e ^ cb31) & 7) << 3)] = t1v.u[e];
            }
            __syncthreads();   // drains K gld16 (long since landed); tile kt+1 visible
        }
    }

    // ---- epilogue: O rows q = (r&3)+8(r>>2)+4hi; l via shuffles ----
    #pragma unroll
    for (int r = 0; r < 16; ++r) {
        const int ql = (r & 3) + 8 * (r >> 2) + 4 * hi;
        const float lb = __shfl(l_l, ql, 64);
        const int qi = q0 + (w << 5) + ql;
        if (qi < SEQ) {
            const float inv = 1.0f / lb;
            ctx[(long)(b * SEQ + qi) * EMBED + h * HDIM + l31] = f2bf(acco[0][r] * inv);
            ctx[(long)(b * SEQ + qi) * EMBED + h * HDIM + 32 + l31] = f2bf(acco[1][r] * inv);
        }
    }
}

// ---------------- Output projection (bf16 MFMA, BM=128 x BN=64, BK=64, T2 swizzle) ----------------
// grid 65 x 12 = 780 blocks (3.0/CU, was 1.5 at 128x128). 4 waves as 2x2 of 64x32 sub-tiles.
// Per-output K-accumulation sequence identical to the 128x128 version -> bit-identical result.
__global__ __launch_bounds__(256)
void proj_mfma_kernel(const unsigned short* __restrict__ ctxbf,
                      const unsigned short* __restrict__ pwbf,
                      const float* __restrict__ bias, float* __restrict__ out)
{
    __shared__ unsigned short As[128][64];
    __shared__ unsigned short Bs[64][64];
    const int m0 = blockIdx.x * 128;
    const int n0 = blockIdx.y * 64;
    const int tid = threadIdx.x;
    const int w = tid >> 6, lane = tid & 63;
    const int li = lane & 15, lg = lane >> 4;
    const int wr = w >> 1, wc = w & 1;

    f32x4 acc[4][2];
    #pragma unroll
    for (int mi = 0; mi < 4; ++mi)
        #pragma unroll
        for (int nj = 0; nj < 2; ++nj) acc[mi][nj] = (f32x4){0.f, 0.f, 0.f, 0.f};

    for (int kt = 0; kt < 12; ++kt) {
        const int k0 = kt << 6;
        #pragma unroll
        for (int c = 0; c < 4; ++c) {          // A: 1024 chunks
            const int idx = c * 256 + tid;
            const int row = idx >> 3, slot = idx & 7;
            const int ss = (slot ^ ((row ^ (row >> 3)) & 7)) << 3;
            int grow = m0 + row; if (grow > MROWS - 1) grow = MROWS - 1;
            gld16(&ctxbf[(long)grow * EMBED + k0 + ss], &As[0][0] + idx * 8);
        }
        #pragma unroll
        for (int c = 0; c < 2; ++c) {          // B: 512 chunks
            const int idx = c * 256 + tid;
            const int row = idx >> 3, slot = idx & 7;
            const int ss = (slot ^ ((row ^ (row >> 3)) & 7)) << 3;
            gld16(&pwbf[(long)(n0 + row) * EMBED + k0 + ss], &Bs[0][0] + idx * 8);
        }
        __syncthreads();

        __builtin_amdgcn_s_setprio(1);
        #pragma unroll
        for (int kk = 0; kk < 2; ++kk) {
            bf16x8 af[4], bfr[2];
            #pragma unroll
            for (int mi = 0; mi < 4; ++mi) {
                const int row = wr * 64 + mi * 16 + li;
                const int s = ((kk * 4 + lg) ^ ((row ^ (row >> 3)) & 7)) << 3;
                af[mi] = *reinterpret_cast<const bf16x8*>(&As[row][s]);
            }
            #pragma unroll
            for (int nj = 0; nj < 2; ++nj) {
                const int row = wc * 32 + nj * 16 + li;
                const int s = ((kk * 4 + lg) ^ ((row ^ (row >> 3)) & 7)) << 3;
                bfr[nj] = *reinterpret_cast<const bf16x8*>(&Bs[row][s]);
            }
            #pragma unroll
            for (int mi = 0; mi < 4; ++mi)
                #pragma unroll
                for (int nj = 0; nj < 2; ++nj)
                    acc[mi][nj] = __builtin_amdgcn_mfma_f32_16x16x32_bf16(
                        af[mi], bfr[nj], acc[mi][nj], 0, 0, 0);
        }
        __builtin_amdgcn_s_setprio(0);
        __syncthreads();
    }

    #pragma unroll
    for (int nj = 0; nj < 2; ++nj) {
        const int n = n0 + wc * 32 + nj * 16 + li;
        const float bn = bias[n];
        #pragma unroll
        for (int mi = 0; mi < 4; ++mi)
            #pragma unroll
            for (int r = 0; r < 4; ++r) {
                const int m = m0 + wr * 64 + mi * 16 + lg * 4 + r;
                if (m < MROWS)
                    out[(long)m * EMBED + n] = acc[mi][nj][r] + bn;
            }
    }
}

extern "C" void kernel_launch(void* const* d_in, const int* in_sizes, int n_in,
                              void* d_out, int out_size, void* d_ws, size_t ws_size,
                              hipStream_t stream) {
    const float* x       = (const float*)d_in[0];
    const float* qkv_w   = (const float*)d_in[1];
    const float* qkv_b   = (const float*)d_in[2];
    const float* proj_w  = (const float*)d_in[3];
    const float* proj_b  = (const float*)d_in[4];
    const float* rel_bt  = (const float*)d_in[5];
    const unsigned char* kmask = (const unsigned char*)d_in[6];
    float* out = (float*)d_out;

    unsigned short* qbuf  = (unsigned short*)d_ws;
    unsigned short* kbuf  = qbuf + QKV_ELEMS;
    unsigned short* vbuf  = kbuf + QKV_ELEMS;
    unsigned short* ctxbf = vbuf + QKV_ELEMS;
    unsigned short* xbf   = ctxbf + QKV_ELEMS;
    unsigned short* wbf   = xbf + QKV_ELEMS;            // 2304*768
    unsigned short* pwbf  = wbf + QKV_N * EMBED;        // 768*768
    float* cosT = (float*)(pwbf + EMBED * EMBED);
    float* sinT = cosT + 1024 * HDIM;
    float* btT  = sinT + 1024 * HDIM;                   // 12*3969 fp32
    unsigned char* maskpad = (unsigned char*)(btT + NHEADS * BT_N);  // 8*1088

    const int ntot4 = NX4 + NW4 + NP4;
    f2bf3_kernel<<<(ntot4 + 255) / 256, 256, 0, stream>>>(x, qkv_w, proj_w, xbf, wbf, pwbf);
    setup_tables_kernel<<<256 + 187 + NBATCH, 256, 0, stream>>>(
        rel_bt, btT, kmask, maskpad, cosT, sinT);

    qkv_mfma_kernel<<<dim3((MROWS + 127) / 128, QKV_N / 128), 256, 0, stream>>>(
        xbf, wbf, qkv_b, cosT, sinT, qbuf, kbuf, vbuf);
    attn_mfma_kernel<<<9 * BHCOUNT, 256, 0, stream>>>(
        qbuf, kbuf, vbuf, btT, maskpad, ctxbf);
    proj_mfma_kernel<<<dim3((MROWS + 127) / 128, EMBED / 64), 256, 0, stream>>>(
        ctxbf, pwbf, proj_b, out);
}

// Round 19
// 216.154 us; speedup vs baseline: 1.0199x; 1.0199x over previous
//
#include <hip/hip_runtime.h>
#include <math.h>

#define EMBED 768
#define NHEADS 12
#define HDIM 64
#define SEQ 1025
#define NBATCH 8
#define BHCOUNT (NBATCH*NHEADS)   // 96
#define MROWS (NBATCH*SEQ)        // 8200
#define QKV_N (3*EMBED)           // 2304
#define QKV_ELEMS (BHCOUNT*SEQ*HDIM)  // 6,297,600 elems (== MROWS*EMBED)
#define BT_N 3969                 // (2*32-1)^2
#define MASKPAD 1088              // 4-aligned padded mask row
// q pre-scale = 0.125 * log2(e): softmax runs in exp2 domain
#define QMUL 0.1803368801111204f
#define LOG2E 1.4426950408889634f
#define NX4 1574400               // MROWS*EMBED/4
#define NW4 442368                // QKV_N*EMBED/4
#define NP4 147456                // EMBED*EMBED/4

typedef __attribute__((ext_vector_type(8))) short bf16x8;
typedef __attribute__((ext_vector_type(4))) float f32x4;
typedef __attribute__((ext_vector_type(16))) float f32x16;
typedef __attribute__((ext_vector_type(4))) unsigned int u32x4;

#define FM3(a,b,c) fmaxf(fmaxf((a),(b)),(c))

static __device__ inline unsigned short f2bf(float f) {
    unsigned u = __float_as_uint(f);
    unsigned r = (u + 0x7FFF + ((u >> 16) & 1)) >> 16;   // RNE
    return (unsigned short)r;
}

// HW pack: two f32 -> one u32 of 2x bf16 (RNE), single VALU op (T12 recipe)
static __device__ inline unsigned int cvtpk(float a, float b) {
    unsigned int r;
    asm("v_cvt_pk_bf16_f32 %0, %1, %2" : "=v"(r) : "v"(a), "v"(b));
    return r;
}

// async global->LDS, 16B per lane, linear LDS dest (wave-uniform base + lane*16)
static __device__ inline void gld16(const unsigned short* g, unsigned short* l) {
    __builtin_amdgcn_global_load_lds(
        (const __attribute__((address_space(1))) unsigned int*)g,
        (__attribute__((address_space(3))) unsigned int*)l,
        16, 0, 0);
}

// ---------------- merged fp32 -> bf16 convert for x, qkv_w, proj_w ----------------
__global__ __launch_bounds__(256)
void f2bf3_kernel(const float* __restrict__ x, const float* __restrict__ w,
                  const float* __restrict__ pw,
                  unsigned short* __restrict__ xbf, unsigned short* __restrict__ wbf,
                  unsigned short* __restrict__ pwbf)
{
    int i = blockIdx.x * 256 + threadIdx.x;   // float4-group index
    const float* src; unsigned short* dst; int off;
    if (i < NX4)            { src = x;  dst = xbf;  off = i; }
    else if (i < NX4 + NW4) { src = w;  dst = wbf;  off = i - NX4; }
    else if (i < NX4 + NW4 + NP4) { src = pw; dst = pwbf; off = i - NX4 - NW4; }
    else return;
    float4 v = *reinterpret_cast<const float4*>(&src[off << 2]);
    ushort4 o;
    o.x = f2bf(v.x); o.y = f2bf(v.y); o.z = f2bf(v.z); o.w = f2bf(v.w);
    *reinterpret_cast<ushort4*>(&dst[off << 2]) = o;
}

// ---------------- merged tables: rope cos/sin + btT (scaled) + mask pad ----------------
__global__ __launch_bounds__(256)
void setup_tables_kernel(const float* __restrict__ bt, float* __restrict__ btT,
                         const unsigned char* __restrict__ m, unsigned char* __restrict__ mp,
                         float* __restrict__ cosT, float* __restrict__ sinT)
{
    const int bid = blockIdx.x, tid = threadIdx.x;
    if (bid < 256) {                       // rope: 4 s-values per block
        int s = (bid << 2) + (tid >> 6);
        int d = tid & 63;
        int pos = (d < 32) ? (s >> 5) : (s & 31);
        int j = (d & 31) >> 1;
        float ang = (float)pos * expf(-(float)j * 0.5756462732485115f);
        cosT[(s << 6) + d] = cosf(ang);
        sinT[(s << 6) + d] = sinf(ang);
    } else if (bid < 256 + 187) {          // btT: 12*3969 elems
        int e = (bid - 256) * 256 + tid;
        if (e < NHEADS * BT_N) {
            int h = e / BT_N, idx = e - h * BT_N;
            btT[h * BT_N + idx] = bt[idx * NHEADS + h] * LOG2E;
        }
    } else {                               // mask pad: 8 blocks
        int b = bid - 443;
        for (int i = tid; i < MASKPAD; i += 256)
            mp[b * MASKPAD + i] = (i < SEQ) ? m[b * SEQ + i] : (unsigned char)0;
    }
}

// ---------------- QKV GEMM (bf16 MFMA, BK=64, T2-swizzled LDS) ----------------
// 128x128 tile, 12 K-iters of 64; As/Bs rows 128B -> XOR-swizzle slot^((row^(row>>3))&7),
// written via pre-swizzled gld16 SOURCE (LDS dest linear), read with the same involution.
__global__ __launch_bounds__(256)
void qkv_mfma_kernel(const unsigned short* __restrict__ xbf,
                     const unsigned short* __restrict__ wbf,
                     const float* __restrict__ bias,
                     const float* __restrict__ cosT, const float* __restrict__ sinT,
                     unsigned short* __restrict__ qout, unsigned short* __restrict__ kout,
                     unsigned short* __restrict__ vout)
{
    __shared__ unsigned short As[128][64];
    __shared__ unsigned short Bs[128][64];
    const int m0 = blockIdx.x * 128;
    const int n0 = blockIdx.y * 128;
    const int tid = threadIdx.x;
    const int w = tid >> 6, lane = tid & 63;
    const int li = lane & 15, lg = lane >> 4;
    const int wr = w >> 1, wc = w & 1;

    f32x4 acc[4][4];
    #pragma unroll
    for (int mi = 0; mi < 4; ++mi)
        #pragma unroll
        for (int nj = 0; nj < 4; ++nj) acc[mi][nj] = (f32x4){0.f, 0.f, 0.f, 0.f};

    for (int kt = 0; kt < 12; ++kt) {
        const int k0 = kt << 6;
        #pragma unroll
        for (int c = 0; c < 4; ++c) {
            const int idx = c * 256 + tid;        // 0..1023
            const int row = idx >> 3, slot = idx & 7;
            const int ss = (slot ^ ((row ^ (row >> 3)) & 7)) << 3;   // swizzled ushort col
            int grow = m0 + row; if (grow > MROWS - 1) grow = MROWS - 1;
            gld16(&xbf[(long)grow * EMBED + k0 + ss], &As[0][0] + idx * 8);
            gld16(&wbf[(long)(n0 + row) * EMBED + k0 + ss], &Bs[0][0] + idx * 8);
        }
        __syncthreads();

        __builtin_amdgcn_s_setprio(1);
        #pragma unroll
        for (int kk = 0; kk < 2; ++kk) {
            bf16x8 af[4], bfr[4];
            #pragma unroll
            for (int mi = 0; mi < 4; ++mi) {
                const int row = wr * 64 + mi * 16 + li;
                const int s = ((kk * 4 + lg) ^ ((row ^ (row >> 3)) & 7)) << 3;
                af[mi] = *reinterpret_cast<const bf16x8*>(&As[row][s]);
            }
            #pragma unroll
            for (int nj = 0; nj < 4; ++nj) {
                const int row = wc * 64 + nj * 16 + li;
                const int s = ((kk * 4 + lg) ^ ((row ^ (row >> 3)) & 7)) << 3;
                bfr[nj] = *reinterpret_cast<const bf16x8*>(&Bs[row][s]);
            }
            #pragma unroll
            for (int mi = 0; mi < 4; ++mi)
                #pragma unroll
                for (int nj = 0; nj < 4; ++nj)
                    acc[mi][nj] = __builtin_amdgcn_mfma_f32_16x16x32_bf16(
                        af[mi], bfr[nj], acc[mi][nj], 0, 0, 0);
        }
        __builtin_amdgcn_s_setprio(0);
        __syncthreads();
    }

    int brow[4][4], srow[4][4];
    #pragma unroll
    for (int mi = 0; mi < 4; ++mi)
        #pragma unroll
        for (int r = 0; r < 4; ++r) {
            int m = m0 + wr * 64 + mi * 16 + lg * 4 + r;
            int mm = (m < MROWS) ? m : (MROWS - 1);
            int bb = mm / SEQ;
            brow[mi][r] = bb;
            srow[mi][r] = mm - bb * SEQ;
        }

    #pragma unroll
    for (int nj = 0; nj < 4; ++nj) {
        const int n = n0 + wc * 64 + nj * 16 + li;
        const int which = n / EMBED;
        const int nh = n - which * EMBED;
        const int h = nh >> 6, d = nh & 63;
        unsigned short* outp = (which == 0) ? qout : (which == 1) ? kout : vout;
        const float mul = (which == 0) ? QMUL : 1.0f;
        const float bn = bias[n];
        const bool dorope = which < 2;
        const float sgn = (d & 1) ? 1.f : -1.f;
        #pragma unroll
        for (int mi = 0; mi < 4; ++mi)
            #pragma unroll
            for (int r = 0; r < 4; ++r) {
                const int m = m0 + wr * 64 + mi * 16 + lg * 4 + r;
                float v = acc[mi][nj][r] + bn;
                float pv = __shfl_xor(v, 1, 64);
                if (m < MROWS) {
                    const int bb = brow[mi][r], s = srow[mi][r];
                    if (dorope && s >= 1) {
                        const int p = s - 1;
                        v = v * cosT[(p << 6) + d] + sgn * pv * sinT[(p << 6) + d];
                    }
                    outp[((long)(bb * NHEADS + h) * SEQ + s) * HDIM + d] = f2bf(v * mul);
                }
            }
    }
}

// ---------------- Flash attention: 32x32 MFMA, in-register P, bias-in-C, scalar mask ----------------
// grid 864 = 9 q-tiles x 96 bh, XCD-clustered: xcd=i&7, jb=i>>3, bh=xcd*12+jb%12,
// q0=(jb/12)*128. Block 256 (4 waves); wave w owns q rows q0+w*32..+31.
// S^T C-layout: accs[j][reg] = S[q = w*32 + (lane&31)][kv = j*32 + (reg&3)+8*(reg>>2)+4*(lane>>5)].
__global__ __launch_bounds__(256)
void attn_mfma_kernel(const unsigned short* __restrict__ qg,
                      const unsigned short* __restrict__ kg,
                      const unsigned short* __restrict__ vg,
                      const float* __restrict__ btT,
                      const unsigned char* __restrict__ maskpad,
                      unsigned short* __restrict__ ctx)
{
    __shared__ unsigned short Ks[2][64][64];    // [buf][kv][d], col ^= ((row^(row>>3))&7)<<3
    __shared__ unsigned short Vts[2][64][64];   // [buf][d][kv], col ^= ((row^(row>>3))&7)<<3

    const int i = (int)blockIdx.x;
    const int xcd = i & 7, jb = i >> 3;
    const int bh = xcd * 12 + (jb % 12);
    const int q0 = (jb / 12) * 128;
    const int b = bh / NHEADS, h = bh % NHEADS;
    const int tid = threadIdx.x;
    const int w = tid >> 6;
    const int lane = tid & 63;
    const int l31 = lane & 31;
    const int hi = lane >> 5;

    const unsigned short* qbase = qg + (long)bh * (SEQ * HDIM);
    const unsigned short* kbase = kg + (long)bh * (SEQ * HDIM);
    const unsigned short* vbase = vg + (long)bh * (SEQ * HDIM);
    const unsigned char* maskp = maskpad + b * MASKPAD;
    const float* btTh = btT + h * BT_N;

    // staging geometry (per thread): 2 chunks, row = idx>>3, col8 = (idx&7)*8
    const int sidx0 = tid, sidx1 = 256 + tid;
    const int sr0 = sidx0 >> 3, sc0 = (sidx0 & 7) << 3;
    const int sr1 = sidx1 >> 3, sc1 = (sidx1 & 7) << 3;
    const int kswz0 = ((sr0 ^ (sr0 >> 3)) & 7) << 3;
    const int kswz1 = ((sr1 ^ (sr1 >> 3)) & 7) << 3;

    // ---- prologue: tile-0 K via gld16 (pre-swizzled src), tile-0 V to regs, Q to regs ----
    gld16(&kbase[(long)sr0 * HDIM + (sc0 ^ kswz0)], &Ks[0][0][0] + sidx0 * 8);
    gld16(&kbase[(long)sr1 * HDIM + (sc1 ^ kswz1)], &Ks[0][0][0] + sidx1 * 8);
    int4 vreg[2];
    vreg[0] = *reinterpret_cast<const int4*>(&vbase[(long)sr0 * HDIM + sc0]);
    vreg[1] = *reinterpret_cast<const int4*>(&vbase[(long)sr1 * HDIM + sc1]);

    const int qrow = (w << 5) + l31;
    const int qi_l = q0 + qrow;
    const int qiq = (qi_l > SEQ - 1) ? (SEQ - 1) : qi_l;
    bf16x8 qf[4];   // B-operand: col q = l31, k-run d = s*16 + hi*8 + 0..7
    #pragma unroll
    for (int s = 0; s < 4; ++s)
        qf[s] = *reinterpret_cast<const bf16x8*>(&qbase[(long)qiq * HDIM + s * 16 + hi * 8]);

    const float bq = (qi_l >= 1) ? 1.0f : 0.0f;
    int qp = qi_l - 1; if (qp < 0) qp = 0; if (qp > 1023) qp = 1023;
    const int qcode = (qp >> 5) * 63 + (qp & 31) + 1984;

    __syncthreads();   // K0 gld16 landed (barrier drains vmcnt); vreg ready
    {
        union { int4 v; unsigned short u[8]; } t0, t1;
        t0.v = vreg[0]; t1.v = vreg[1];
        const int cb30 = sc0 >> 3, cb31 = sc1 >> 3;
        #pragma unroll
        for (int e = 0; e < 8; ++e) {
            Vts[0][sc0 + e][sr0 ^ (((e ^ cb30) & 7) << 3)] = t0.u[e];
            Vts[0][sc1 + e][sr1 ^ (((e ^ cb31) & 7) << 3)] = t1.u[e];
        }
    }
    __syncthreads();   // tile 0 fully staged

    float m_l = -1e30f, l_l = 0.f;
    f32x16 acco[2];    // O[q=(reg&3)+8(reg>>2)+4hi][d = j2*32 + l31]
    #pragma unroll
    for (int r = 0; r < 16; ++r) { acco[0][r] = 0.f; acco[1][r] = 0.f; }

    int kcb[2][4];     // incremental bias code base per (j, quad)
    for (int kt = 0; kt < 17; ++kt) {
        const int k0 = kt * 64;
        const int cur = kt & 1;

        // ---- (1) prefetch next tile's K (gld16) + V (regs) ----
        if (kt < 16) {
            const int k0n = k0 + 64;
            vreg[0] = (k0n + sr0 < SEQ)
                ? *reinterpret_cast<const int4*>(&vbase[(long)(k0n + sr0) * HDIM + sc0])
                : make_int4(0, 0, 0, 0);
            vreg[1] = (k0n + sr1 < SEQ)
                ? *reinterpret_cast<const int4*>(&vbase[(long)(k0n + sr1) * HDIM + sc1])
                : make_int4(0, 0, 0, 0);
            int ki0 = k0n + sr0; if (ki0 > SEQ - 1) ki0 = SEQ - 1;
            int ki1 = k0n + sr1; if (ki1 > SEQ - 1) ki1 = SEQ - 1;
            gld16(&kbase[(long)ki0 * HDIM + (sc0 ^ kswz0)], &Ks[cur ^ 1][0][0] + sidx0 * 8);
            gld16(&kbase[(long)ki1 * HDIM + (sc1 ^ kswz1)], &Ks[cur ^ 1][0][0] + sidx1 * 8);
        }

        // ---- (2)+(3) bias values; mask via wave-uniform scalar screen on interior tiles ----
        float bvf[2][16];
        unsigned int b4[2][4];
        unsigned int anym = 0;
        const bool interior = (kt >= 1 && kt <= 15);
        if (interior) {
            // wave-uniform mask check: 4 uniform uint4 loads + SALU OR-reduce
            const uint4 ma_ = *reinterpret_cast<const uint4*>(&maskp[k0]);
            const uint4 mb_ = *reinterpret_cast<const uint4*>(&maskp[k0 + 16]);
            const uint4 mc_ = *reinterpret_cast<const uint4*>(&maskp[k0 + 32]);
            const uint4 md_ = *reinterpret_cast<const uint4*>(&maskp[k0 + 48]);
            anym = (ma_.x | ma_.y | ma_.z | ma_.w) | (mb_.x | mb_.y | mb_.z | mb_.w) |
                   (mc_.x | mc_.y | mc_.z | mc_.w) | (md_.x | md_.y | md_.z | md_.w);
            #pragma unroll
            for (int j = 0; j < 2; ++j)
                #pragma unroll
                for (int t = 0; t < 4; ++t) {
                    kcb[j][t] += 126;
                    const int base = qcode - kcb[j][t];   // r=0 index, in [0,3968]
                    if (t == 0 && hi == 0) {
                        // crossing: codes c, c+32, c+33, c+34
                        float4 f = *reinterpret_cast<const float4*>(&btTh[base - 34]);
                        bvf[j][0] = btTh[base]; bvf[j][1] = f.z;
                        bvf[j][2] = f.y;        bvf[j][3] = f.x;
                    } else {
                        float4 f = *reinterpret_cast<const float4*>(&btTh[base - 3]);
                        bvf[j][t * 4 + 0] = f.w; bvf[j][t * 4 + 1] = f.z;
                        bvf[j][t * 4 + 2] = f.y; bvf[j][t * 4 + 3] = f.x;
                    }
                }
        } else {
            #pragma unroll
            for (int j = 0; j < 2; ++j)
                #pragma unroll
                for (int t = 0; t < 4; ++t) {
                    unsigned int bb = 0;
                    #pragma unroll
                    for (int ri = 0; ri < 4; ++ri) {
                        const int ki = k0 + j * 32 + t * 8 + hi * 4 + ri;
                        const int kic = (ki > SEQ - 1) ? (SEQ - 1) : ki;
                        unsigned int dead = (ki >= SEQ) ? 1u : (unsigned int)maskp[kic];
                        bb |= (dead ? 1u : 0u) << (ri * 8);
                        int kp = ki - 1; if (kp < 0) kp = 0; if (kp > 1023) kp = 1023;
                        const int kcv = (kp >> 5) * 63 + (kp & 31);
                        bvf[j][t * 4 + ri] = btTh[qcode - kcv];
                    }
                    b4[j][t] = bb;
                    if (kt == 0) {
                        // seed exact chain with UNCLAMPED kp (kv=0 -> -32); CLS handled below
                        const int kp0 = j * 32 + t * 8 + hi * 4 - 1;
                        kcb[j][t] = (kp0 >> 5) * 63 + (kp0 & 31);
                    }
                }
        }

        // ---- (4) S^T = K · Q^T (32x32x16), bias pre-loaded into the C-operand ----
        if (kt == 0 && hi == 0) bvf[0][0] = 0.0f;   // CLS column kv=0: no bias for any q
        f32x16 accs[2];
        #pragma unroll
        for (int j = 0; j < 2; ++j)
            #pragma unroll
            for (int r = 0; r < 16; ++r)
                accs[j][r] = bvf[j][r] * bq;
        __builtin_amdgcn_s_setprio(1);
        #pragma unroll
        for (int j = 0; j < 2; ++j) {
            const int rswz = ((l31 ^ (j * 4 + (l31 >> 3))) & 7) << 3;
            const unsigned short* krow = &Ks[cur][j * 32 + l31][0];
            #pragma unroll
            for (int s = 0; s < 4; ++s) {
                bf16x8 kf = *reinterpret_cast<const bf16x8*>(&krow[(s * 16 + hi * 8) ^ rswz]);
                accs[j] = __builtin_amdgcn_mfma_f32_32x32x16_bf16(kf, qf[s], accs[j], 0, 0, 0);
            }
        }
        __builtin_amdgcn_s_setprio(0);

        // ---- (5) mask application (cold paths only) ----
        if (interior) {
            if (anym) {   // wave-uniform, rare
                #pragma unroll
                for (int j = 0; j < 2; ++j)
                    #pragma unroll
                    for (int t = 0; t < 4; ++t)
                        #pragma unroll
                        for (int ri = 0; ri < 4; ++ri)
                            if (maskp[k0 + j * 32 + t * 8 + hi * 4 + ri])
                                accs[j][t * 4 + ri] = -1e30f;
            }
        } else {
            if (__any((b4[0][0] | b4[0][1] | b4[0][2] | b4[0][3] |
                       b4[1][0] | b4[1][1] | b4[1][2] | b4[1][3]) != 0)) {
                #pragma unroll
                for (int j = 0; j < 2; ++j)
                    #pragma unroll
                    for (int r = 0; r < 16; ++r)
                        if ((b4[j][r >> 2] >> ((r & 3) * 8)) & 0xFF) accs[j][r] = -1e30f;
            }
        }

        // ---- (6) in-register row softmax (v_max3 tree) with defer-max ----
        float t0 = FM3(accs[0][0],  accs[0][1],  accs[0][2]);
        float t1 = FM3(accs[0][3],  accs[0][4],  accs[0][5]);
        float t2 = FM3(accs[0][6],  accs[0][7],  accs[0][8]);
        float t3 = FM3(accs[0][9],  accs[0][10], accs[0][11]);
        float t4 = FM3(accs[0][12], accs[0][13], accs[0][14]);
        float t5 = FM3(accs[0][15], accs[1][0],  accs[1][1]);
        float t6 = FM3(accs[1][2],  accs[1][3],  accs[1][4]);
        float t7 = FM3(accs[1][5],  accs[1][6],  accs[1][7]);
        float t8 = FM3(accs[1][8],  accs[1][9],  accs[1][10]);
        float t9 = FM3(accs[1][11], accs[1][12], accs[1][13]);
        float u0 = FM3(t0, t1, t2);
        float u1 = FM3(t3, t4, t5);
        float u2 = FM3(t6, t7, t8);
        float u3 = FM3(t9, accs[1][14], accs[1][15]);
        float mx = fmaxf(FM3(u0, u1, u2), u3);
        mx = fmaxf(mx, __shfl_xor(mx, 32, 64));
        if (__any(mx > m_l + 8.0f)) {
            const float mnew = fmaxf(m_l, mx);
            const float alpha = __builtin_amdgcn_exp2f(m_l - mnew);
            #pragma unroll
            for (int r = 0; r < 16; ++r) {
                const float al = __shfl(alpha, (r & 3) + 8 * (r >> 2) + 4 * hi, 64);
                acco[0][r] *= al;
                acco[1][r] *= al;
            }
            l_l *= alpha;
            m_l = mnew;
        }
        float rs = 0.f;
        #pragma unroll
        for (int j = 0; j < 2; ++j)
            #pragma unroll
            for (int r = 0; r < 16; ++r) {
                accs[j][r] = __builtin_amdgcn_exp2f(accs[j][r] - m_l);
                rs += accs[j][r];
            }
        rs += __shfl_xor(rs, 32, 64);
        l_l += rs;

        // ---- (6b) P -> bf16 A-fragments in-register: 16 cvt_pk + 8 permlane32_swap ----
        unsigned int W[2][8];
        #pragma unroll
        for (int j = 0; j < 2; ++j)
            #pragma unroll
            for (int p = 0; p < 8; ++p)
                W[j][p] = cvtpk(accs[j][2 * p], accs[j][2 * p + 1]);
        #pragma unroll
        for (int j = 0; j < 2; ++j)
            #pragma unroll
            for (int sg = 0; sg < 2; ++sg) {
                unsigned int a0 = W[j][4 * sg + 0], a2 = W[j][4 * sg + 2];
                asm volatile("v_permlane32_swap_b32 %0, %1" : "+v"(a0), "+v"(a2));
                W[j][4 * sg + 0] = a0; W[j][4 * sg + 2] = a2;
                unsigned int a1 = W[j][4 * sg + 1], a3 = W[j][4 * sg + 3];
                asm volatile("v_permlane32_swap_b32 %0, %1" : "+v"(a1), "+v"(a3));
                W[j][4 * sg + 1] = a1; W[j][4 * sg + 3] = a3;
            }

        // ---- (7) PV: O += P · V (32x32x16) ----
        __builtin_amdgcn_s_setprio(1);
        #pragma unroll
        for (int j2 = 0; j2 < 2; ++j2) {
            const int vswz = ((l31 ^ (j2 * 4 + (l31 >> 3))) & 7) << 3;
            const unsigned short* vrow = &Vts[cur][j2 * 32 + l31][0];
            #pragma unroll
            for (int s = 0; s < 4; ++s) {
                bf16x8 vf = *reinterpret_cast<const bf16x8*>(&vrow[(s * 16 + hi * 8) ^ vswz]);
                u32x4 aw;
                aw[0] = W[s >> 1][4 * (s & 1) + 0];
                aw[1] = W[s >> 1][4 * (s & 1) + 1];
                aw[2] = W[s >> 1][4 * (s & 1) + 2];
                aw[3] = W[s >> 1][4 * (s & 1) + 3];
                bf16x8 pa = __builtin_bit_cast(bf16x8, aw);
                acco[j2] = __builtin_amdgcn_mfma_f32_32x32x16_bf16(pa, vf, acco[j2], 0, 0, 0);
            }
        }
        __builtin_amdgcn_s_setprio(0);

        // ---- (8) drain V regs into next buffer; single barrier per tile ----
        if (kt < 16) {
            union { int4 v; unsigned short u[8]; } t0v, t1v;
            t0v.v = vreg[0]; t1v.v = vreg[1];
            const int cb30 = sc0 >> 3, cb31 = sc1 >> 3;
            #pragma unroll
            for (int e = 0; e < 8; ++e) {
                Vts[cur ^ 1][sc0 + e][sr0 ^ (((e ^ cb30) & 7) << 3)] = t0v.u[e];
                Vts[cur ^ 1][sc1 + e][sr1 ^ (((e ^ cb31) & 7) << 3)] = t1v.u[e];
            }
            __syncthreads();   // drains K gld16 (long since landed); tile kt+1 visible
        }
    }

    // ---- epilogue: O rows q = (r&3)+8(r>>2)+4hi; l via shuffles ----
    #pragma unroll
    for (int r = 0; r < 16; ++r) {
        const int ql = (r & 3) + 8 * (r >> 2) + 4 * hi;
        const float lb = __shfl(l_l, ql, 64);
        const int qi = q0 + (w << 5) + ql;
        if (qi < SEQ) {
            const float inv = 1.0f / lb;
            ctx[(long)(b * SEQ + qi) * EMBED + h * HDIM + l31] = f2bf(acco[0][r] * inv);
            ctx[(long)(b * SEQ + qi) * EMBED + h * HDIM + 32 + l31] = f2bf(acco[1][r] * inv);
        }
    }
}

// ---------------- Output projection (bf16 MFMA, BK=64, T2-swizzled LDS) ----------------
__global__ __launch_bounds__(256)
void proj_mfma_kernel(const unsigned short* __restrict__ ctxbf,
                      const unsigned short* __restrict__ pwbf,
                      const float* __restrict__ bias, float* __restrict__ out)
{
    __shared__ unsigned short As[128][64];
    __shared__ unsigned short Bs[128][64];
    const int m0 = blockIdx.x * 128;
    const int n0 = blockIdx.y * 128;
    const int tid = threadIdx.x;
    const int w = tid >> 6, lane = tid & 63;
    const int li = lane & 15, lg = lane >> 4;
    const int wr = w >> 1, wc = w & 1;

    f32x4 acc[4][4];
    #pragma unroll
    for (int mi = 0; mi < 4; ++mi)
        #pragma unroll
        for (int nj = 0; nj < 4; ++nj) acc[mi][nj] = (f32x4){0.f, 0.f, 0.f, 0.f};

    for (int kt = 0; kt < 12; ++kt) {
        const int k0 = kt << 6;
        #pragma unroll
        for (int c = 0; c < 4; ++c) {
            const int idx = c * 256 + tid;        // 0..1023
            const int row = idx >> 3, slot = idx & 7;
            const int ss = (slot ^ ((row ^ (row >> 3)) & 7)) << 3;
            int grow = m0 + row; if (grow > MROWS - 1) grow = MROWS - 1;
            gld16(&ctxbf[(long)grow * EMBED + k0 + ss], &As[0][0] + idx * 8);
            gld16(&pwbf[(long)(n0 + row) * EMBED + k0 + ss], &Bs[0][0] + idx * 8);
        }
        __syncthreads();

        __builtin_amdgcn_s_setprio(1);
        #pragma unroll
        for (int kk = 0; kk < 2; ++kk) {
            bf16x8 af[4], bfr[4];
            #pragma unroll
            for (int mi = 0; mi < 4; ++mi) {
                const int row = wr * 64 + mi * 16 + li;
                const int s = ((kk * 4 + lg) ^ ((row ^ (row >> 3)) & 7)) << 3;
                af[mi] = *reinterpret_cast<const bf16x8*>(&As[row][s]);
            }
            #pragma unroll
            for (int nj = 0; nj < 4; ++nj) {
                const int row = wc * 64 + nj * 16 + li;
                const int s = ((kk * 4 + lg) ^ ((row ^ (row >> 3)) & 7)) << 3;
                bfr[nj] = *reinterpret_cast<const bf16x8*>(&Bs[row][s]);
            }
            #pragma unroll
            for (int mi = 0; mi < 4; ++mi)
                #pragma unroll
                for (int nj = 0; nj < 4; ++nj)
                    acc[mi][nj] = __builtin_amdgcn_mfma_f32_16x16x32_bf16(
                        af[mi], bfr[nj], acc[mi][nj], 0, 0, 0);
        }
        __builtin_amdgcn_s_setprio(0);
        __syncthreads();
    }

    #pragma unroll
    for (int nj = 0; nj < 4; ++nj) {
        const int n = n0 + wc * 64 + nj * 16 + li;
        const float bn = bias[n];
        #pragma unroll
        for (int mi = 0; mi < 4; ++mi)
            #pragma unroll
            for (int r = 0; r < 4; ++r) {
                const int m = m0 + wr * 64 + mi * 16 + lg * 4 + r;
                if (m < MROWS)
                    out[(long)m * EMBED + n] = acc[mi][nj][r] + bn;
            }
    }
}

extern "C" void kernel_launch(void* const* d_in, const int* in_sizes, int n_in,
                              void* d_out, int out_size, void* d_ws, size_t ws_size,
                              hipStream_t stream) {
    const float* x       = (const float*)d_in[0];
    const float* qkv_w   = (const float*)d_in[1];
    const float* qkv_b   = (const float*)d_in[2];
    const float* proj_w  = (const float*)d_in[3];
    const float* proj_b  = (const float*)d_in[4];
    const float* rel_bt  = (const float*)d_in[5];
    const unsigned char* kmask = (const unsigned char*)d_in[6];
    float* out = (float*)d_out;

    unsigned short* qbuf  = (unsigned short*)d_ws;
    unsigned short* kbuf  = qbuf + QKV_ELEMS;
    unsigned short* vbuf  = kbuf + QKV_ELEMS;
    unsigned short* ctxbf = vbuf + QKV_ELEMS;
    unsigned short* xbf   = ctxbf + QKV_ELEMS;
    unsigned short* wbf   = xbf + QKV_ELEMS;            // 2304*768
    unsigned short* pwbf  = wbf + QKV_N * EMBED;        // 768*768
    float* cosT = (float*)(pwbf + EMBED * EMBED);
    float* sinT = cosT + 1024 * HDIM;
    float* btT  = sinT + 1024 * HDIM;                   // 12*3969 fp32
    unsigned char* maskpad = (unsigned char*)(btT + NHEADS * BT_N);  // 8*1088

    const int ntot4 = NX4 + NW4 + NP4;
    f2bf3_kernel<<<(ntot4 + 255) / 256, 256, 0, stream>>>(x, qkv_w, proj_w, xbf, wbf, pwbf);
    setup_tables_kernel<<<256 + 187 + NBATCH, 256, 0, stream>>>(
        rel_bt, btT, kmask, maskpad, cosT, sinT);

    qkv_mfma_kernel<<<dim3((MROWS + 127) / 128, QKV_N / 128), 256, 0, stream>>>(
        xbf, wbf, qkv_b, cosT, sinT, qbuf, kbuf, vbuf);
    attn_mfma_kernel<<<9 * BHCOUNT, 256, 0, stream>>>(
        qbuf, kbuf, vbuf, btT, maskpad, ctxbf);
    proj_mfma_kernel<<<dim3((MROWS + 127) / 128, EMBED / 128), 256, 0, stream>>>(
        ctxbf, pwbf, proj_b, out);
}